// Round 12
// baseline (3121.605 us; speedup 1.0000x reference)
//
#include <hip/hip_runtime.h>
#include <math.h>

constexpr int NB = 256, NT = 64, DS = 128, DA = 32, DB = 1024, DH = 1024, DE = 1024;
constexpr float MIN_STD = 0.1f;

constexpr size_t OUT_PS  = (size_t)NT * NB * DB;
constexpr size_t OUT_PM  = OUT_PS  + (size_t)NT * NB * DS;
constexpr size_t OUT_PSD = OUT_PM  + (size_t)NT * NB * DS;
constexpr size_t OUT_QS  = OUT_PSD + (size_t)NT * NB * DS;
constexpr size_t OUT_QM  = OUT_QS  + (size_t)NT * NB * DS;
constexpr size_t OUT_QSD = OUT_QM  + (size_t)NT * NB * DS;

typedef __attribute__((ext_vector_type(8))) short bf8_t;
typedef __attribute__((ext_vector_type(4))) float f4_t;
#define MFMA16(a, b, c) __builtin_amdgcn_mfma_f32_16x16x32_bf16((a), (b), (c), 0, 0, 0)
#define SWZ8(ch, row) ((ch & ~7) | ((ch & 7) ^ ((row) & 7)))

__device__ __forceinline__ short f2bf(float f) {
    union { float f; unsigned u; } v; v.f = f;
    unsigned r = v.u + 0x7FFF + ((v.u >> 16) & 1);
    return (short)(r >> 16);
}
__device__ __forceinline__ float bf2f(unsigned short h) {
    union { unsigned u; float f; } v; v.u = ((unsigned)h) << 16; return v.f;
}
__device__ __forceinline__ unsigned pack2(float a, float b) {
    return ((unsigned)(unsigned short)f2bf(a)) | (((unsigned)(unsigned short)f2bf(b)) << 16);
}
__device__ __forceinline__ float sigm(float x) { return 1.0f / (1.0f + __expf(-x)); }

// ---------------------------------------------------------------------------
// One-shot conversion of ALL weights to bf16 (+ frag-preswizzles).
// Ranges (8-f32 chunks):
//  Wbp[0,131072) Wbq[..393216) Wsp[..425984) Wsq[..458752) Wsq_sw[..491520)
//  Wsa_sw[..512000) Wbqnb_sw[..643072) Wih_sw[..1036288) Whh_sw[..1429504)
//  Wbqob_sw[..1560576)
// ---------------------------------------------------------------------------
__global__ __launch_bounds__(256) void k_cvt_all(
    const float* __restrict__ Wih, const float* __restrict__ Whh,
    const float* __restrict__ Wbp, const float* __restrict__ Wbq,
    const float* __restrict__ Wsp, const float* __restrict__ Wsq,
    const float* __restrict__ Wsa,
    short* dWbp, short* dWbq, short* dWsp, short* dWsq,
    short* dWsqsw, short* dWsasw, short* dWbqnb, short* dWihsw, short* dWhhsw,
    short* dWbqob)
{
    int i = blockIdx.x * 256 + threadIdx.x;
    if (i >= 1560576) return;
    if (i >= 1429504) {
        // Wbq[:, 1024:2048] frag-preswizzled (obs half)
        int il = i - 1429504;
        int c = il >> 7, kc = il & 127;
        const float4* s4 = (const float4*)Wbq;
        float4 a = s4[(size_t)c * 512 + 256 + kc * 2], b = s4[(size_t)c * 512 + 256 + kc * 2 + 1];
        bf8_t v;
        v[0]=f2bf(a.x); v[1]=f2bf(a.y); v[2]=f2bf(a.z); v[3]=f2bf(a.w);
        v[4]=f2bf(b.x); v[5]=f2bf(b.y); v[6]=f2bf(b.z); v[7]=f2bf(b.w);
        ((bf8_t*)dWbqob)[((size_t)((c >> 4) * 128 + kc)) * 16 + (c & 15)] = v;
        return;
    }
    if (i >= 512000 && i < 643072) {
        int il = i - 512000;
        int c = il >> 7, kc = il & 127;
        const float4* s4 = (const float4*)Wbq;
        float4 a = s4[(size_t)c * 512 + kc * 2], b = s4[(size_t)c * 512 + kc * 2 + 1];
        bf8_t v;
        v[0]=f2bf(a.x); v[1]=f2bf(a.y); v[2]=f2bf(a.z); v[3]=f2bf(a.w);
        v[4]=f2bf(b.x); v[5]=f2bf(b.y); v[6]=f2bf(b.z); v[7]=f2bf(b.w);
        ((bf8_t*)dWbqnb)[((size_t)((c >> 4) * 128 + kc)) * 16 + (c & 15)] = v;
        return;
    }
    const float* src; short* dst; int lo; bool sw = false; int swNCH = 0;
    if      (i <  131072) { src = Wbp; dst = dWbp; lo = 0; }
    else if (i <  393216) { src = Wbq; dst = dWbq; lo = 131072; }
    else if (i <  425984) { src = Wsp; dst = dWsp; lo = 393216; }
    else if (i <  458752) { src = Wsq; dst = dWsq; lo = 425984; }
    else if (i <  491520) { src = Wsq; dst = dWsqsw; lo = 458752; sw = true; swNCH = 128; }
    else if (i <  512000) { src = Wsa; dst = dWsasw; lo = 491520; sw = true; swNCH = 20; }
    else if (i < 1036288) { src = Wih; dst = dWihsw; lo = 643072;  sw = true; swNCH = 128; }
    else                  { src = Whh; dst = dWhhsw; lo = 1036288; sw = true; swNCH = 128; }
    int il = i - lo;
    const float4* s4 = (const float4*)src;
    float4 a = s4[il * 2], b = s4[il * 2 + 1];
    bf8_t v;
    v[0]=f2bf(a.x); v[1]=f2bf(a.y); v[2]=f2bf(a.z); v[3]=f2bf(a.w);
    v[4]=f2bf(b.x); v[5]=f2bf(b.y); v[6]=f2bf(b.z); v[7]=f2bf(b.w);
    if (!sw) ((bf8_t*)dst)[il] = v;
    else {
        int row = il / swNCH, ch = il % swNCH;
        ((bf8_t*)dst)[((row >> 4) * swNCH + ch) * 16 + (row & 15)] = v;
    }
}

// ---------------------------------------------------------------------------
// kobs: obs_pre = obs @ Wbq[:,1024:2048]^T + b_bq (bf16), all 64 steps.
// One block per 64-row A-tile; A staged ONCE in LDS (128KB bf16), loop 16
// j-tiles streaming B-frags direct from preswizzled Wbqob_sw. grid 256 x 512.
// ---------------------------------------------------------------------------
__global__ __launch_bounds__(512) void kobs(
    const float* __restrict__ obsA, const short* __restrict__ Wbqob_sw,
    const float* __restrict__ b_bq, short* __restrict__ dst)
{
    __shared__ __align__(16) char smem[147456];
    bf8_t* A = (bf8_t*)smem;                   // [64][128] swz = 128KB
    float* ebuf = (float*)(smem + 131072);     // [64][64] f32 = 16KB

    const int tx = threadIdx.x;
    const int wv = tx >> 6, lane = tx & 63;
    const int ar = lane & 15, kq = lane >> 4;
    const int b0 = blockIdx.x * 64;
    const int ct = wv & 3, rt0 = (wv >> 2) * 2;

    // stage A (f32 -> bf16, swizzled): 8192 chunks / 512 thr
    #pragma unroll
    for (int i = 0; i < 16; ++i) {
        int c = tx + i * 512;
        int row = c >> 7, ch = c & 127;
        const float4* p4 = (const float4*)(obsA + (size_t)(b0 + row) * DE + ch * 8);
        float4 f0 = p4[0], f1 = p4[1];
        bf8_t v;
        v[0]=f2bf(f0.x); v[1]=f2bf(f0.y); v[2]=f2bf(f0.z); v[3]=f2bf(f0.w);
        v[4]=f2bf(f1.x); v[5]=f2bf(f1.y); v[6]=f2bf(f1.z); v[7]=f2bf(f1.w);
        A[row * 128 + SWZ8(ch, row)] = v;
    }
    __syncthreads();

    for (int jt = 0; jt < 16; ++jt) {
        f4_t acc[2];
        acc[0] = (f4_t)0.0f; acc[1] = (f4_t)0.0f;
        for (int ks = 0; ks < 32; ++ks) {
            int ch = ks * 4 + kq;
            bf8_t bfr = *(const bf8_t*)(Wbqob_sw +
                (((size_t)(jt * 4 + ct) * 128 + ch) * 16 + ar) * 8);
            #pragma unroll
            for (int r = 0; r < 2; ++r) {
                int row = (rt0 + r) * 16 + ar;
                bf8_t a = A[row * 128 + SWZ8(ch, row)];
                acc[r] = MFMA16(a, bfr, acc[r]);
            }
        }
        #pragma unroll
        for (int r = 0; r < 2; ++r)
            #pragma unroll
            for (int q = 0; q < 4; ++q)
                ebuf[((rt0 + r) * 16 + kq * 4 + q) * 64 + ct * 16 + ar] = acc[r][q];
        __syncthreads();
        {   // coalesced store: 512 thr x 8 cols
            int row = tx >> 3, p = tx & 7;
            float* src = ebuf + row * 64 + p * 8;
            int colb = jt * 64 + p * 8;
            uint2 u;
            u.x = pack2(src[0] + b_bq[colb],     src[1] + b_bq[colb + 1]);
            u.y = pack2(src[2] + b_bq[colb + 2], src[3] + b_bq[colb + 3]);
            uint2 u2;
            u2.x = pack2(src[4] + b_bq[colb + 4], src[5] + b_bq[colb + 5]);
            u2.y = pack2(src[6] + b_bq[colb + 6], src[7] + b_bq[colb + 7]);
            uint4 w; w.x = u.x; w.y = u.y; w.z = u2.x; w.w = u2.y;
            *(uint4*)(dst + (size_t)(b0 + row) * DB + colb) = w;
        }
        __syncthreads();
    }
}

// ---------------------------------------------------------------------------
// kstep: one dispatch/step, 1024 thr. Wave-specialized software pipeline:
// x-waves (0-7): P1 -> Q -> sample -> X -> gi ; h-waves (8-15): gh GEMM
// split into 4 K-chunks overlapping intervals I1-I4. Shared full barriers.
// ---------------------------------------------------------------------------
__global__ __launch_bounds__(1024) void kstep(
    int t,
    const float* __restrict__ prev_state, const float* __restrict__ actions_t,
    const float* __restrict__ nonterm, const float* __restrict__ post_noise,
    const short* __restrict__ part_in, const short* __restrict__ obs_pre_tm1,
    const short* __restrict__ Wsq_sw, const float* __restrict__ b_sq,
    const short* __restrict__ Wsa_sw, const float* __restrict__ b_sa,
    const short* __restrict__ Wih_sw, const short* __restrict__ Whh_sw,
    const float* __restrict__ b_ih, const float* __restrict__ b_hh,
    const short* __restrict__ Wbqnb_sw,
    const float* __restrict__ belp,
    float* __restrict__ bel_out, short* __restrict__ part_out,
    float* __restrict__ o_qm, float* __restrict__ o_qsd, float* __restrict__ o_qs)
{
    __shared__ __align__(16) char smem[136960];
    short* R1s = (short*)smem;                 // [16][1024] swz bf16 (hq / x)
    bf8_t* R18 = (bf8_t*)smem;
    bf8_t* hf8 = (bf8_t*)(smem + 32768);       // [16][128] swz (belief*nt)
    bf8_t* sP  = (bf8_t*)(smem + 32768);       // P5 stage (reuses hf8 after B5)
    short* sPs = (short*)(smem + 32768);
    short* saS = (short*)(smem + 65536);       // [16][168]
    bf8_t* sa8 = (bf8_t*)(smem + 65536);       // [16][21]
    float* exg = (float*)(smem + 70912);       // [16 slots][3][16][16] f32
    float* qex = (float*)(smem + 120064);      // [16][257] f32 (non-aliasing)

    const int tx = threadIdx.x, bid = blockIdx.x;
    const int wv = tx >> 6, lane = tx & 63;
    const int ar = lane & 15, kq = lane >> 4;
    const int bgrp = bid >> 4, low = bid & 15;
    const int jt = ((low & 7) << 1) | (low >> 3);   // XCD-pinned col slice
    const int b0 = bgrp * 16, j0 = jt * 64;
    const float* ntp = (t > 0) ? nonterm + (size_t)(t - 1) * NB : nullptr;
    const bool xside = (wv < 8);
    const int wx = wv & 7;

    // h-side gh state (lives across intervals)
    f4_t hacc[3];
    hacc[0] = (f4_t)0.0f; hacc[1] = (f4_t)0.0f; hacc[2] = (f4_t)0.0f;
    const int hkh = wx >> 2, hwn = wx & 3;

#define GH_PART(K0)                                                            \
    {                                                                          \
        _Pragma("unroll")                                                      \
        for (int k16 = (K0); k16 < (K0) + 4; ++k16) {                          \
            int chunk = hkh * 64 + k16 * 4 + kq;                               \
            bf8_t a = hf8[ar * 128 + SWZ8(chunk, ar)];                         \
            _Pragma("unroll")                                                  \
            for (int g = 0; g < 3; ++g) {                                      \
                bf8_t bfr = *(const bf8_t*)(Whh_sw +                           \
                    (((size_t)(g * 64 + jt * 4 + hwn) * 128 + chunk) * 16 + ar) * 8); \
                hacc[g] = MFMA16(a, bfr, hacc[g]);                             \
            }                                                                  \
        }                                                                      \
    }

    // I0: stage h = belp*nt (bf16, swizzled) — all threads
    #pragma unroll
    for (int i = 0; i < 2; ++i) {
        int c = tx + i * 1024;
        int row = c >> 7, ch = c & 127;
        int b = b0 + row;
        const float4* p4 = (const float4*)(belp + (size_t)b * DB + ch * 8);
        float4 f0 = p4[0], f1 = p4[1];
        float ntv = ntp ? ntp[b] : 1.0f;
        bf8_t v;
        v[0]=f2bf(f0.x*ntv); v[1]=f2bf(f0.y*ntv); v[2]=f2bf(f0.z*ntv); v[3]=f2bf(f0.w*ntv);
        v[4]=f2bf(f1.x*ntv); v[5]=f2bf(f1.y*ntv); v[6]=f2bf(f1.z*ntv); v[7]=f2bf(f1.w*ntv);
        hf8[row * 128 + SWZ8(ch, row)] = v;
    }
    __syncthreads();   // B0

    // I1: x: P1 (or state stage) + actions ; h: gh k16 0..3
    if (xside) {
        if (t > 0) {
            #pragma unroll
            for (int i = 0; i < 4; ++i) {
                int c = tx + i * 512;
                int row = c >> 7, ch = c & 127;
                const bf8_t o8 = ((const bf8_t*)obs_pre_tm1)[(size_t)(b0 + row) * 128 + ch];
                float s[8];
                #pragma unroll
                for (int e = 0; e < 8; ++e) s[e] = bf2f((unsigned short)o8[e]);
                #pragma unroll
                for (int p = 0; p < 16; ++p) {
                    const bf8_t v = ((const bf8_t*)part_in)[((size_t)p * NB + b0 + row) * 128 + ch];
                    #pragma unroll
                    for (int e = 0; e < 8; ++e) s[e] += bf2f((unsigned short)v[e]);
                }
                bf8_t r;
                #pragma unroll
                for (int e = 0; e < 8; ++e) r[e] = f2bf(fmaxf(s[e], 0.0f));
                R18[row * 128 + SWZ8(ch, row)] = r;
            }
        } else {
            #pragma unroll
            for (int i = 0; i < 4; ++i) {
                int c = tx + i * 512;
                int row = c >> 7, col = c & 127;
                saS[row * 168 + col] = f2bf(prev_state[(size_t)(b0 + row) * DS + col]);
            }
        }
        {   // actions: 512 entries, one per x-thread
            int row = tx >> 5, ac = tx & 31;
            saS[row * 168 + 128 + ac] = f2bf(actions_t[(size_t)(b0 + row) * DA + ac]);
        }
    } else {
        GH_PART(0)
    }
    __syncthreads();   // B1

    // I2: x: Q (2 out-tiles/wave) ; h: gh 4..7
    if (xside) {
        if (t > 0) {
            #pragma unroll
            for (int tt = 0; tt < 2; ++tt) {
                int tile = wx + tt * 8;
                f4_t qa[4];
                #pragma unroll
                for (int i = 0; i < 4; ++i) qa[i] = (f4_t)0.0f;
                for (int ks = 0; ks < 32; ks += 4) {
                    #pragma unroll
                    for (int u = 0; u < 4; ++u) {
                        int ch = (ks + u) * 4 + kq;
                        bf8_t a = R18[ar * 128 + SWZ8(ch, ar)];
                        bf8_t bfr = *(const bf8_t*)(Wsq_sw +
                            ((size_t)(tile * 128 + ch)) * 128 + ar * 8);
                        qa[u] = MFMA16(a, bfr, qa[u]);
                    }
                }
                f4_t qs_ = (qa[0] + qa[1]) + (qa[2] + qa[3]);
                #pragma unroll
                for (int r = 0; r < 4; ++r)
                    qex[(kq * 4 + r) * 257 + tile * 16 + ar] = qs_[r];
            }
        }
    } else {
        GH_PART(4)
    }
    __syncthreads();   // B2

    // I3: x: sample -> outputs + saS ; h: gh 8..11
    if (xside) {
        if (t > 0) {
            #pragma unroll
            for (int i = 0; i < 4; ++i) {
                int e = tx + i * 512;
                int row = e >> 7, col = e & 127;
                int b = b0 + row;
                float m  = qex[row * 257 + col] + b_sq[col];
                float sr = qex[row * 257 + 128 + col] + b_sq[128 + col];
                float sd = log1pf(__expf(-fabsf(sr))) + fmaxf(sr, 0.0f) + MIN_STD;
                float n_ = post_noise[((size_t)(t - 1) * NB + b) * DS + col];
                float qs = fmaf(sd, n_, m);
                if (jt == 0) {
                    size_t off = ((size_t)(t - 1) * NB + b) * DS + col;
                    o_qm[off] = m; o_qsd[off] = sd; o_qs[off] = qs;
                }
                saS[row * 168 + col] = f2bf(qs * ntp[b]);
            }
        }
    } else {
        GH_PART(8)
    }
    __syncthreads();   // B3

    // I4: x: X (8 tiles/wave) ; h: gh 12..15 + exg writes
    if (xside) {
        f4_t xacc[8];
        #pragma unroll
        for (int i = 0; i < 8; ++i) xacc[i] = (f4_t)0.0f;
        #pragma unroll
        for (int ks = 0; ks < 5; ++ks) {
            int ch = ks * 4 + kq;
            bf8_t a = sa8[ar * 21 + ch];
            #pragma unroll
            for (int i = 0; i < 8; ++i) {
                int tile = wx * 8 + i;
                bf8_t bfr = *(const bf8_t*)(Wsa_sw +
                    ((size_t)(tile * 20 + ch)) * 128 + ar * 8);
                xacc[i] = MFMA16(a, bfr, xacc[i]);
            }
        }
        #pragma unroll
        for (int i = 0; i < 8; ++i) {
            int col = (wx * 8 + i) * 16 + ar;
            float bj = b_sa[col];
            int chunk = col >> 3, el = col & 7;
            #pragma unroll
            for (int r = 0; r < 4; ++r) {
                int row = kq * 4 + r;
                R1s[row * 1024 + SWZ8(chunk, row) * 8 + el] =
                    f2bf(fmaxf(xacc[i][r] + bj, 0.0f));
            }
        }
    } else {
        GH_PART(12)
        const int slot = hkh * 8 + 4 + hwn;
        #pragma unroll
        for (int g = 0; g < 3; ++g)
            #pragma unroll
            for (int r = 0; r < 4; ++r)
                exg[((slot * 3 + g) * 16 + (kq * 4 + r)) * 16 + ar] = hacc[g][r];
    }
    __syncthreads();   // B4

    // I5: x: gi (full K/2 per wave) + exg writes ; h: idle
    if (xside) {
        const int ikh = wx >> 2, iwn = wx & 3;
        f4_t acc[3];
        acc[0] = (f4_t)0.0f; acc[1] = (f4_t)0.0f; acc[2] = (f4_t)0.0f;
        #pragma unroll 4
        for (int k16 = 0; k16 < 16; ++k16) {
            int chunk = ikh * 64 + k16 * 4 + kq;
            bf8_t a = R18[ar * 128 + SWZ8(chunk, ar)];
            #pragma unroll
            for (int g = 0; g < 3; ++g) {
                bf8_t bfr = *(const bf8_t*)(Wih_sw +
                    (((size_t)(g * 64 + jt * 4 + iwn) * 128 + chunk) * 16 + ar) * 8);
                acc[g] = MFMA16(a, bfr, acc[g]);
            }
        }
        const int slot = ikh * 8 + iwn;
        #pragma unroll
        for (int g = 0; g < 3; ++g)
            #pragma unroll
            for (int r = 0; r < 4; ++r)
                exg[((slot * 3 + g) * 16 + (kq * 4 + r)) * 16 + ar] = acc[g][r];
    }
    __syncthreads();   // B5

    // I6: distributed finisher — all 1024 threads, one (row,col) each
    {
        const int row = tx >> 6;
        const int col = tx & 63;
        const int wn2 = col >> 4, cl = col & 15;
        const int j = j0 + col;
        float gi[3], gh[3];
        #pragma unroll
        for (int g = 0; g < 3; ++g) {
            gi[g] = exg[(((0  + wn2) * 3 + g) * 16 + row) * 16 + cl]
                  + exg[(((8  + wn2) * 3 + g) * 16 + row) * 16 + cl];
            gh[g] = exg[(((4  + wn2) * 3 + g) * 16 + row) * 16 + cl]
                  + exg[(((12 + wn2) * 3 + g) * 16 + row) * 16 + cl];
        }
        const int b = b0 + row;
        const float ntv = ntp ? ntp[b] : 1.0f;
        const float h = belp[(size_t)b * DB + j] * ntv;
        const float rr = sigm(gi[0] + b_ih[j] + gh[0] + b_hh[j]);
        const float zz = sigm(gi[1] + b_ih[DB + j] + gh[1] + b_hh[DB + j]);
        const float nn = tanhf(gi[2] + b_ih[2 * DB + j] + rr * (gh[2] + b_hh[2 * DB + j]));
        const float nbv = (1.0f - zz) * nn + zz * h;
        bel_out[(size_t)b * DB + j] = nbv;
        sPs[row * 64 + ((((col >> 3) ^ (row & 7)) << 3) | (col & 7))] = f2bf(nbv);
    }
    __syncthreads();   // B6

    // I7: P5: partial[jt] = nb_slice @ Wbqnb[:, K-slice jt]^T  (16 waves)
    {
        f4_t pacc[4];
        #pragma unroll
        for (int i = 0; i < 4; ++i) pacc[i] = (f4_t)0.0f;
        #pragma unroll
        for (int ks = 0; ks < 2; ++ks) {
            int ch = ks * 4 + kq;
            bf8_t a = sP[ar * 8 + (ch ^ (ar & 7))];
            #pragma unroll
            for (int i = 0; i < 4; ++i) {
                int tile = wv * 4 + i;
                bf8_t bfr = *(const bf8_t*)(Wbqnb_sw +
                    (((size_t)tile * 128 + jt * 8 + ch) * 16 + ar) * 8);
                pacc[i] = MFMA16(a, bfr, pacc[i]);
            }
        }
        #pragma unroll
        for (int i = 0; i < 4; ++i) {
            int c = (wv * 4 + i) * 16 + ar;
            #pragma unroll
            for (int r = 0; r < 4; ++r)
                part_out[((size_t)jt * NB + b0 + kq * 4 + r) * DB + c] = f2bf(pacc[i][r]);
        }
    }
#undef GH_PART
}

// ---------------------------------------------------------------------------
// khq63: hq[63] = relu(sum partials + obs_pre[63]) -> hqb bf16. (proven R6)
// ---------------------------------------------------------------------------
__global__ __launch_bounds__(256) void khq63(
    const short* __restrict__ partials, const short* __restrict__ obs_pre,
    short* __restrict__ hqb)
{
    const int row = blockIdx.x;
    const int c = threadIdx.x * 4;
    const ushort4 o = *(const ushort4*)(obs_pre + (size_t)row * DB + c);
    float s0 = bf2f(o.x), s1 = bf2f(o.y), s2 = bf2f(o.z), s3 = bf2f(o.w);
    for (int p = 0; p < 16; ++p) {
        const ushort4 v = *(const ushort4*)(partials + ((size_t)p * NB + row) * DB + c);
        s0 += bf2f(v.x); s1 += bf2f(v.y); s2 += bf2f(v.z); s3 += bf2f(v.w);
    }
    uint2 u;
    u.x = pack2(fmaxf(s0, 0.0f), fmaxf(s1, 0.0f));
    u.y = pack2(fmaxf(s2, 0.0f), fmaxf(s3, 0.0f));
    *(uint2*)(hqb + (size_t)row * DB + c) = u;
}

// ---------------------------------------------------------------------------
// kout: [mean|sd] = A @ W^T + b; softplus; sample. (proven; b-tile fastest)
// ---------------------------------------------------------------------------
__global__ __launch_bounds__(256) void kout(
    const short* __restrict__ A_, const short* __restrict__ W_,
    const float* __restrict__ bias, const float* __restrict__ noise,
    float* __restrict__ om, float* __restrict__ osd, float* __restrict__ os)
{
    __shared__ __align__(16) char smem[12288];
    const int tx = threadIdx.x;
    const int wv = tx >> 6, lane = tx & 63;
    const int b0 = blockIdx.x * 64, i0 = blockIdx.y * 16;
    const int wm = wv & 1, wn = wv >> 1;
    const bf8_t* A8 = (const bf8_t*)A_;
    const bf8_t* W8 = (const bf8_t*)W_;
    bf8_t* sA = (bf8_t*)smem;
    bf8_t* sB = sA + 512;
    f4_t acc[2];
    acc[0] = (f4_t)0.0f; acc[1] = (f4_t)0.0f;

    for (int kt = 0; kt < DH; kt += 64) {
        #pragma unroll
        for (int i = 0; i < 2; ++i) {
            int c = tx + i * 256;
            int row = c >> 3, ch = c & 7;
            sA[row * 8 + (ch ^ (row & 7))] = A8[(size_t)(b0 + row) * 128 + (kt >> 3) + ch];
        }
        {
            int row = tx >> 3, ch = tx & 7;
            int wr = (row < 16) ? (i0 + row) : (128 + i0 + (row - 16));
            sB[row * 8 + (ch ^ (row & 7))] = W8[(size_t)wr * 128 + (kt >> 3) + ch];
        }
        __syncthreads();
        #pragma unroll
        for (int ks = 0; ks < 2; ++ks) {
            int ch = ks * 4 + (lane >> 4);
            bf8_t a[2], b;
            #pragma unroll
            for (int mi = 0; mi < 2; ++mi) {
                int row = wm * 32 + mi * 16 + (lane & 15);
                a[mi] = sA[row * 8 + (ch ^ (row & 7))];
            }
            {
                int row = wn * 16 + (lane & 15);
                b = sB[row * 8 + (ch ^ (row & 7))];
            }
            acc[0] = MFMA16(a[0], b, acc[0]);
            acc[1] = MFMA16(a[1], b, acc[1]);
        }
        __syncthreads();
    }
    float* ebuf = (float*)smem;
    #pragma unroll
    for (int mi = 0; mi < 2; ++mi)
        #pragma unroll
        for (int r = 0; r < 4; ++r) {
            int row = wm * 32 + mi * 16 + (lane >> 4) * 4 + r;
            int col = wn * 16 + (lane & 15);
            ebuf[row * 32 + col] = acc[mi][r];
        }
    __syncthreads();
    {
        int bl = tx >> 2, p = tx & 3;
        int b = b0 + bl;
        float4 vm, vs, vx;
        #pragma unroll
        for (int k = 0; k < 4; ++k) {
            int i = p * 4 + k;
            float m_ = ebuf[bl * 32 + i] + bias[i0 + i];
            float sraw = ebuf[bl * 32 + 16 + i] + bias[128 + i0 + i];
            float sd = log1pf(__expf(-fabsf(sraw))) + fmaxf(sraw, 0.0f) + MIN_STD;
            float n_ = noise[(size_t)b * DS + i0 + i];
            ((float*)&vm)[k] = m_;
            ((float*)&vs)[k] = sd;
            ((float*)&vx)[k] = fmaf(sd, n_, m_);
        }
        size_t off = (size_t)b * DS + i0 + p * 4;
        *(float4*)(om + off)  = vm;
        *(float4*)(osd + off) = vs;
        *(float4*)(os + off)  = vx;
    }
}

// ---------------------------------------------------------------------------
// khp: hp = relu(beliefs @ W_bp^T + b_bp), 8192-row chunk. (proven)
// ---------------------------------------------------------------------------
__global__ __launch_bounds__(256) void khp(
    const float* __restrict__ belA, const short* __restrict__ Wbp_bf,
    const float* __restrict__ b_bp, short* __restrict__ hp_bf)
{
    __shared__ __align__(16) char smem[16384];
    const int tx = threadIdx.x;
    const int wv = tx >> 6, lane = tx & 63;
    const int b0 = blockIdx.x * 64, j0 = blockIdx.y * 64;
    const int wm = wv & 1, wn = wv >> 1;
    const bf8_t* Wp8 = (const bf8_t*)Wbp_bf;
    bf8_t* sA = (bf8_t*)smem;
    bf8_t* sB = sA + 512;
    f4_t acc[2][2];
    acc[0][0] = (f4_t)0.0f; acc[0][1] = (f4_t)0.0f;
    acc[1][0] = (f4_t)0.0f; acc[1][1] = (f4_t)0.0f;

    for (int kt = 0; kt < DB; kt += 64) {
        #pragma unroll
        for (int i = 0; i < 2; ++i) {
            int c = tx + i * 256;
            int row = c >> 3, ch = c & 7;
            const float4* p4 = (const float4*)(belA + (size_t)(b0 + row) * DB + kt + ch * 8);
            float4 f0 = p4[0], f1 = p4[1];
            bf8_t v;
            v[0]=f2bf(f0.x); v[1]=f2bf(f0.y); v[2]=f2bf(f0.z); v[3]=f2bf(f0.w);
            v[4]=f2bf(f1.x); v[5]=f2bf(f1.y); v[6]=f2bf(f1.z); v[7]=f2bf(f1.w);
            sA[row * 8 + (ch ^ (row & 7))] = v;
            sB[row * 8 + (ch ^ (row & 7))] = Wp8[(size_t)(j0 + row) * 128 + (kt >> 3) + ch];
        }
        __syncthreads();
        #pragma unroll
        for (int ks = 0; ks < 2; ++ks) {
            int ch = ks * 4 + (lane >> 4);
            bf8_t a[2], b[2];
            #pragma unroll
            for (int mi = 0; mi < 2; ++mi) {
                int row = wm * 32 + mi * 16 + (lane & 15);
                a[mi] = sA[row * 8 + (ch ^ (row & 7))];
            }
            #pragma unroll
            for (int ni = 0; ni < 2; ++ni) {
                int row = wn * 32 + ni * 16 + (lane & 15);
                b[ni] = sB[row * 8 + (ch ^ (row & 7))];
            }
            #pragma unroll
            for (int mi = 0; mi < 2; ++mi)
                #pragma unroll
                for (int ni = 0; ni < 2; ++ni)
                    acc[mi][ni] = MFMA16(a[mi], b[ni], acc[mi][ni]);
        }
        __syncthreads();
    }
    float* ebuf = (float*)smem;
    #pragma unroll
    for (int mi = 0; mi < 2; ++mi)
        #pragma unroll
        for (int ni = 0; ni < 2; ++ni)
            #pragma unroll
            for (int r = 0; r < 4; ++r) {
                int row = wm * 32 + mi * 16 + (lane >> 4) * 4 + r;
                int col = wn * 32 + ni * 16 + (lane & 15);
                ebuf[row * 64 + col] = fmaxf(acc[mi][ni][r] + b_bp[j0 + col], 0.0f);
            }
    __syncthreads();
    {
        int bl = tx >> 2, p = tx & 3;
        float* src = ebuf + bl * 64 + p * 16;
        short* dst = hp_bf + (size_t)(b0 + bl) * DH + j0 + p * 16;
        #pragma unroll
        for (int q = 0; q < 4; ++q) {
            uint2 u; u.x = pack2(src[q*4], src[q*4+1]); u.y = pack2(src[q*4+2], src[q*4+3]);
            *(uint2*)(dst + q * 4) = u;
        }
    }
}

// ---------------------------------------------------------------------------
extern "C" void kernel_launch(void* const* d_in, const int* in_sizes, int n_in,
                              void* d_out, int out_size, void* d_ws, size_t ws_size,
                              hipStream_t stream)
{
    const float* prev_state   = (const float*)d_in[0];
    const float* actions      = (const float*)d_in[1];
    const float* prev_belief  = (const float*)d_in[2];
    const float* observations = (const float*)d_in[3];
    const float* nonterm      = (const float*)d_in[4];
    const float* prior_noise  = (const float*)d_in[5];
    const float* post_noise   = (const float*)d_in[6];
    const float* W_sa = (const float*)d_in[7];
    const float* b_sa = (const float*)d_in[8];
    const float* W_ih = (const float*)d_in[9];
    const float* W_hh = (const float*)d_in[10];
    const float* b_ih = (const float*)d_in[11];
    const float* b_hh = (const float*)d_in[12];
    const float* W_bp = (const float*)d_in[13];
    const float* b_bp = (const float*)d_in[14];
    const float* W_sp = (const float*)d_in[15];
    const float* b_sp = (const float*)d_in[16];
    const float* W_bq = (const float*)d_in[17];
    const float* b_bq = (const float*)d_in[18];
    const float* W_sq = (const float*)d_in[19];
    const float* b_sq = (const float*)d_in[20];

    float* out     = (float*)d_out;
    float* beliefs = out;
    float* o_ps  = out + OUT_PS;
    float* o_pm  = out + OUT_PM;
    float* o_psd = out + OUT_PSD;
    float* o_qs  = out + OUT_QS;
    float* o_qm  = out + OUT_QM;
    float* o_qsd = out + OUT_QSD;

    // workspace (shorts)
    short* w = (short*)d_ws;
    short* Wbp_bf   = w;                                  // 1048576
    short* Wbq_bf   = Wbp_bf   + (size_t)1048576;         // 2097152
    short* Wsp_bf   = Wbq_bf   + (size_t)2097152;         // 262144
    short* Wsq_bf   = Wsp_bf   + (size_t)262144;          // 262144
    short* Wsq_sw   = Wsq_bf   + (size_t)262144;          // 262144
    short* Wsa_sw   = Wsq_sw   + (size_t)262144;          // 163840
    short* Wbqnb_sw = Wsa_sw   + (size_t)163840;          // 1048576
    short* Wbqob_sw = Wbqnb_sw + (size_t)1048576;         // 1048576
    short* Wih_sw   = Wbqob_sw + (size_t)1048576;         // 3145728
    short* Whh_sw   = Wih_sw   + (size_t)3145728;         // 3145728
    short* obs_all  = Whh_sw   + (size_t)3145728;         // 16777216
    short* partials = obs_all  + (size_t)16777216;        // 8388608
    short* hqb      = partials + (size_t)8388608;         // 262144
    short* hp_bf    = partials;                           // tail reuse
    const size_t PART = (size_t)16 * NB * DB;

    k_cvt_all<<<6096, 256, 0, stream>>>(
        W_ih, W_hh, W_bp, W_bq, W_sp, W_sq, W_sa,
        Wbp_bf, Wbq_bf, Wsp_bf, Wsq_bf, Wsq_sw, Wsa_sw, Wbqnb_sw, Wih_sw, Whh_sw,
        Wbqob_sw);

    // obs_pre for ALL 64 steps: A-resident-in-LDS version
    kobs<<<256, 512, 0, stream>>>(observations, Wbqob_sw, b_bq, obs_all);

    for (int t = 0; t < NT; ++t) {
        const float* belp = (t == 0) ? prev_belief : beliefs + (size_t)(t - 1) * NB * DB;
        kstep<<<256, 1024, 0, stream>>>(
            t, prev_state, actions + (size_t)t * NB * DA,
            nonterm, post_noise,
            partials + ((t & 1) ^ 1) * PART,
            obs_all + (size_t)(t > 0 ? t - 1 : 0) * NB * DB,
            Wsq_sw, b_sq, Wsa_sw, b_sa,
            Wih_sw, Whh_sw, b_ih, b_hh, Wbqnb_sw,
            belp, beliefs + (size_t)t * NB * DB,
            partials + (t & 1) * PART,
            o_qm, o_qsd, o_qs);
    }

    // final-step posterior: hq[63] (sum partials) then outputs
    khq63<<<256, 256, 0, stream>>>(
        partials + ((NT - 1) & 1) * PART, obs_all + (size_t)(NT - 1) * NB * DB, hqb);
    kout<<<dim3(4, 8), 256, 0, stream>>>(
        hqb, Wsq_bf, b_sq, post_noise + (size_t)(NT - 1) * NB * DS,
        o_qm + (size_t)(NT - 1) * NB * DS, o_qsd + (size_t)(NT - 1) * NB * DS,
        o_qs + (size_t)(NT - 1) * NB * DS);

    // prior head: batched, 2 chunks of 8192 rows (hp reuses partials space)
    for (int c = 0; c < 2; ++c) {
        const size_t r0 = (size_t)c * 8192;
        khp<<<dim3(128, 16), 256, 0, stream>>>(
            beliefs + r0 * DB, Wbp_bf, b_bp, hp_bf);
        kout<<<dim3(128, 8), 256, 0, stream>>>(
            hp_bf, Wsp_bf, b_sp, prior_noise + r0 * DS,
            o_pm + r0 * DS, o_psd + r0 * DS, o_ps + r0 * DS);
    }
}

// Round 13
// 2591.036 us; speedup vs baseline: 1.2048x; 1.2048x over previous
//
#include <hip/hip_runtime.h>
#include <math.h>

constexpr int NB = 256, NT = 64, DS = 128, DA = 32, DB = 1024, DH = 1024, DE = 1024;
constexpr float MIN_STD = 0.1f;

constexpr size_t OUT_PS  = (size_t)NT * NB * DB;
constexpr size_t OUT_PM  = OUT_PS  + (size_t)NT * NB * DS;
constexpr size_t OUT_PSD = OUT_PM  + (size_t)NT * NB * DS;
constexpr size_t OUT_QS  = OUT_PSD + (size_t)NT * NB * DS;
constexpr size_t OUT_QM  = OUT_QS  + (size_t)NT * NB * DS;
constexpr size_t OUT_QSD = OUT_QM  + (size_t)NT * NB * DS;

typedef __attribute__((ext_vector_type(8))) short bf8_t;
typedef __attribute__((ext_vector_type(4))) float f4_t;
#define MFMA16(a, b, c) __builtin_amdgcn_mfma_f32_16x16x32_bf16((a), (b), (c), 0, 0, 0)
#define SWZ8(ch, row) ((ch & ~7) | ((ch & 7) ^ ((row) & 7)))

__device__ __forceinline__ short f2bf(float f) {
    union { float f; unsigned u; } v; v.f = f;
    unsigned r = v.u + 0x7FFF + ((v.u >> 16) & 1);
    return (short)(r >> 16);
}
__device__ __forceinline__ float bf2f(unsigned short h) {
    union { unsigned u; float f; } v; v.u = ((unsigned)h) << 16; return v.f;
}
__device__ __forceinline__ unsigned pack2(float a, float b) {
    return ((unsigned)(unsigned short)f2bf(a)) | (((unsigned)(unsigned short)f2bf(b)) << 16);
}
__device__ __forceinline__ float sigm(float x) { return 1.0f / (1.0f + __expf(-x)); }

// ---------------------------------------------------------------------------
// One-shot conversion of ALL weights to bf16 (+ frag-preswizzles). (proven R8)
// ---------------------------------------------------------------------------
__global__ __launch_bounds__(256) void k_cvt_all(
    const float* __restrict__ Wih, const float* __restrict__ Whh,
    const float* __restrict__ Wbp, const float* __restrict__ Wbq,
    const float* __restrict__ Wsp, const float* __restrict__ Wsq,
    const float* __restrict__ Wsa,
    short* dWbp, short* dWbq, short* dWsp, short* dWsq,
    short* dWsqsw, short* dWsasw, short* dWbqnb, short* dWihsw, short* dWhhsw)
{
    int i = blockIdx.x * 256 + threadIdx.x;
    if (i >= 1429504) return;
    if (i >= 512000 && i < 643072) {
        int il = i - 512000;
        int c = il >> 7, kc = il & 127;
        const float4* s4 = (const float4*)Wbq;
        float4 a = s4[(size_t)c * 512 + kc * 2], b = s4[(size_t)c * 512 + kc * 2 + 1];
        bf8_t v;
        v[0]=f2bf(a.x); v[1]=f2bf(a.y); v[2]=f2bf(a.z); v[3]=f2bf(a.w);
        v[4]=f2bf(b.x); v[5]=f2bf(b.y); v[6]=f2bf(b.z); v[7]=f2bf(b.w);
        ((bf8_t*)dWbqnb)[((size_t)((c >> 4) * 128 + kc)) * 16 + (c & 15)] = v;
        return;
    }
    const float* src; short* dst; int lo; bool sw = false; int swNCH = 0;
    if      (i <  131072) { src = Wbp; dst = dWbp; lo = 0; }
    else if (i <  393216) { src = Wbq; dst = dWbq; lo = 131072; }
    else if (i <  425984) { src = Wsp; dst = dWsp; lo = 393216; }
    else if (i <  458752) { src = Wsq; dst = dWsq; lo = 425984; }
    else if (i <  491520) { src = Wsq; dst = dWsqsw; lo = 458752; sw = true; swNCH = 128; }
    else if (i <  512000) { src = Wsa; dst = dWsasw; lo = 491520; sw = true; swNCH = 20; }
    else if (i < 1036288) { src = Wih; dst = dWihsw; lo = 643072;  sw = true; swNCH = 128; }
    else                  { src = Whh; dst = dWhhsw; lo = 1036288; sw = true; swNCH = 128; }
    int il = i - lo;
    const float4* s4 = (const float4*)src;
    float4 a = s4[il * 2], b = s4[il * 2 + 1];
    bf8_t v;
    v[0]=f2bf(a.x); v[1]=f2bf(a.y); v[2]=f2bf(a.z); v[3]=f2bf(a.w);
    v[4]=f2bf(b.x); v[5]=f2bf(b.y); v[6]=f2bf(b.z); v[7]=f2bf(b.w);
    if (!sw) ((bf8_t*)dst)[il] = v;
    else {
        int row = il / swNCH, ch = il % swNCH;
        ((bf8_t*)dst)[((row >> 4) * swNCH + ch) * 16 + (row & 15)] = v;
    }
}

// ---------------------------------------------------------------------------
// kobs: obs_pre = obs @ Wbq[:,1024:2048]^T + b_bq (bf16). (proven R11; ebuf
// padded to stride 72 to break same-bank rows)
// Grid (256 b-tiles, 16 j-tiles) — b fastest => A-tile XCD-pinned mod 8.
// ---------------------------------------------------------------------------
__global__ __launch_bounds__(256) void kobs(
    const float* __restrict__ obsA, const short* __restrict__ Wbq_bf,
    const float* __restrict__ b_bq, short* __restrict__ dst)
{
    __shared__ __align__(16) char smem[18688];
    const int tx = threadIdx.x;
    const int wv = tx >> 6, lane = tx & 63;
    const int b0 = blockIdx.x * 64, j0 = blockIdx.y * 64;
    const int wm = wv & 1, wn = wv >> 1;
    const bf8_t* Wq8 = (const bf8_t*)Wbq_bf;
    bf8_t* sA = (bf8_t*)smem;
    bf8_t* sB = sA + 512;
    f4_t acc[2][2];
    acc[0][0] = (f4_t)0.0f; acc[0][1] = (f4_t)0.0f;
    acc[1][0] = (f4_t)0.0f; acc[1][1] = (f4_t)0.0f;

    for (int kt = 0; kt < DE; kt += 64) {
        #pragma unroll
        for (int i = 0; i < 2; ++i) {
            int c = tx + i * 256;
            int row = c >> 3, ch = c & 7;
            const float4* p4 = (const float4*)(obsA + (size_t)(b0 + row) * DE + kt + ch * 8);
            float4 f0 = p4[0], f1 = p4[1];
            bf8_t v;
            v[0]=f2bf(f0.x); v[1]=f2bf(f0.y); v[2]=f2bf(f0.z); v[3]=f2bf(f0.w);
            v[4]=f2bf(f1.x); v[5]=f2bf(f1.y); v[6]=f2bf(f1.z); v[7]=f2bf(f1.w);
            sA[row * 8 + (ch ^ (row & 7))] = v;
            sB[row * 8 + (ch ^ (row & 7))] = Wq8[(size_t)(j0 + row) * 256 + 128 + (kt >> 3) + ch];
        }
        __syncthreads();
        #pragma unroll
        for (int ks = 0; ks < 2; ++ks) {
            int ch = ks * 4 + (lane >> 4);
            bf8_t a[2], b[2];
            #pragma unroll
            for (int mi = 0; mi < 2; ++mi) {
                int row = wm * 32 + mi * 16 + (lane & 15);
                a[mi] = sA[row * 8 + (ch ^ (row & 7))];
            }
            #pragma unroll
            for (int ni = 0; ni < 2; ++ni) {
                int row = wn * 32 + ni * 16 + (lane & 15);
                b[ni] = sB[row * 8 + (ch ^ (row & 7))];
            }
            #pragma unroll
            for (int mi = 0; mi < 2; ++mi)
                #pragma unroll
                for (int ni = 0; ni < 2; ++ni)
                    acc[mi][ni] = MFMA16(a[mi], b[ni], acc[mi][ni]);
        }
        __syncthreads();
    }
    float* ebuf = (float*)smem;          // [64][72] padded
    #pragma unroll
    for (int mi = 0; mi < 2; ++mi)
        #pragma unroll
        for (int ni = 0; ni < 2; ++ni)
            #pragma unroll
            for (int r = 0; r < 4; ++r) {
                int row = wm * 32 + mi * 16 + (lane >> 4) * 4 + r;
                int col = wn * 32 + ni * 16 + (lane & 15);
                ebuf[row * 72 + col] = acc[mi][ni][r] + b_bq[j0 + col];
            }
    __syncthreads();
    {
        int bl = tx >> 2, p = tx & 3;
        float* src = ebuf + bl * 72 + p * 16;
        short* d = dst + (size_t)(b0 + bl) * DB + j0 + p * 16;
        #pragma unroll
        for (int q = 0; q < 4; ++q) {
            uint2 u; u.x = pack2(src[q*4], src[q*4+1]); u.y = pack2(src[q*4+2], src[q*4+3]);
            *(uint2*)(d + q * 4) = u;
        }
    }
}

// ---------------------------------------------------------------------------
// kstep: one dispatch/step. 1024 thr (16 waves), 16 batch x 64 cols/block.
// jt XCD-pinned. h-stage hoisted -> P1 -> Q -> sample -> X -> G -> finisher -> P5.
// qex de-aliased from R1 (removes the mid-Q barrier).
// ---------------------------------------------------------------------------
__global__ __launch_bounds__(1024) void kstep(
    int t,
    const float* __restrict__ prev_state, const float* __restrict__ actions_t,
    const float* __restrict__ nonterm, const float* __restrict__ post_noise,
    const short* __restrict__ part_in, const short* __restrict__ obs_pre_tm1,
    const short* __restrict__ Wsq_sw, const float* __restrict__ b_sq,
    const short* __restrict__ Wsa_sw, const float* __restrict__ b_sa,
    const short* __restrict__ Wih_sw, const short* __restrict__ Whh_sw,
    const float* __restrict__ b_ih, const float* __restrict__ b_hh,
    const short* __restrict__ Wbqnb_sw,
    const float* __restrict__ belp,
    float* __restrict__ bel_out, short* __restrict__ part_out,
    float* __restrict__ o_qm, float* __restrict__ o_qsd, float* __restrict__ o_qs)
{
    __shared__ __align__(16) char smem[136512];
    short* R1s = (short*)smem;                 // [16][1024] swz bf16 (hq / x)
    bf8_t* R18 = (bf8_t*)smem;
    bf8_t* hf8 = (bf8_t*)(smem + 32768);       // [16][128] swz (belief*nt)
    bf8_t* sP  = (bf8_t*)(smem + 32768);       // [16][8] swz (P5, reuses hf8)
    short* sPs = (short*)(smem + 32768);       // same as sP, short view
    short* saS = (short*)(smem + 65536);       // [16][168]
    bf8_t* sa8 = (bf8_t*)(smem + 65536);       // [16][21]
    float* exg = (float*)(smem + 70912);       // [16wv][3][16][16]
    float* qex = (float*)(smem + 120064);      // [16][257] f32 (de-aliased)

    const int tx = threadIdx.x, bid = blockIdx.x;
    const int wv = tx >> 6, lane = tx & 63;
    const int ar = lane & 15, kq = lane >> 4;
    const int bgrp = bid >> 4, low = bid & 15;
    const int jt = ((low & 7) << 1) | (low >> 3);   // XCD-pinned col slice
    const int b0 = bgrp * 16, j0 = jt * 64;
    const float* ntp = (t > 0) ? nonterm + (size_t)(t - 1) * NB : nullptr;

    // ---- hoisted: stage h = belp*nt (bf16, swizzled) — latency overlaps P1/Q
    #pragma unroll
    for (int i = 0; i < 2; ++i) {
        int c = tx + i * 1024;
        int row = c >> 7, ch = c & 127;
        int b = b0 + row;
        const float4* p4 = (const float4*)(belp + (size_t)b * DB + ch * 8);
        float4 f0 = p4[0], f1 = p4[1];
        float ntv = ntp ? ntp[b] : 1.0f;
        bf8_t v;
        v[0]=f2bf(f0.x*ntv); v[1]=f2bf(f0.y*ntv); v[2]=f2bf(f0.z*ntv); v[3]=f2bf(f0.w*ntv);
        v[4]=f2bf(f1.x*ntv); v[5]=f2bf(f1.y*ntv); v[6]=f2bf(f1.z*ntv); v[7]=f2bf(f1.w*ntv);
        hf8[row * 128 + SWZ8(ch, row)] = v;
    }

    if (t > 0) {
        // ---- P1: hq = relu(sum 16 partials + obs_pre) -> R1 (swizzled) ----
        #pragma unroll
        for (int i = 0; i < 2; ++i) {
            int c = tx + i * 1024;
            int row = c >> 7, ch = c & 127;
            const bf8_t o8 = ((const bf8_t*)obs_pre_tm1)[(size_t)(b0 + row) * 128 + ch];
            float s[8];
            #pragma unroll
            for (int e = 0; e < 8; ++e) s[e] = bf2f((unsigned short)o8[e]);
            #pragma unroll
            for (int p = 0; p < 16; ++p) {
                const bf8_t v = ((const bf8_t*)part_in)[((size_t)p * NB + b0 + row) * 128 + ch];
                #pragma unroll
                for (int e = 0; e < 8; ++e) s[e] += bf2f((unsigned short)v[e]);
            }
            bf8_t r;
            #pragma unroll
            for (int e = 0; e < 8; ++e) r[e] = f2bf(fmaxf(s[e], 0.0f));
            R18[row * 128 + SWZ8(ch, row)] = r;
        }
        __syncthreads();
        // ---- Q: qs = hq @ Wsq^T, 1 out-tile/wave, 4 partial accs ----
        {
            f4_t qa[4];
            #pragma unroll
            for (int i = 0; i < 4; ++i) qa[i] = (f4_t)0.0f;
            for (int ks = 0; ks < 32; ks += 4) {
                #pragma unroll
                for (int u = 0; u < 4; ++u) {
                    int ch = (ks + u) * 4 + kq;
                    bf8_t a = R18[ar * 128 + SWZ8(ch, ar)];
                    bf8_t bfr = *(const bf8_t*)(Wsq_sw +
                        ((size_t)(wv * 128 + ch)) * 128 + ar * 8);
                    qa[u] = MFMA16(a, bfr, qa[u]);
                }
            }
            f4_t qs_ = (qa[0] + qa[1]) + (qa[2] + qa[3]);
            #pragma unroll
            for (int r = 0; r < 4; ++r)
                qex[(kq * 4 + r) * 257 + wv * 16 + ar] = qs_[r];
        }
        __syncthreads();
        #pragma unroll
        for (int i = 0; i < 2; ++i) {
            int e = tx + i * 1024;
            int row = e >> 7, col = e & 127;
            int b = b0 + row;
            float m  = qex[row * 257 + col] + b_sq[col];
            float sr = qex[row * 257 + 128 + col] + b_sq[128 + col];
            float sd = log1pf(__expf(-fabsf(sr))) + fmaxf(sr, 0.0f) + MIN_STD;
            float n_ = post_noise[((size_t)(t - 1) * NB + b) * DS + col];
            float qs = fmaf(sd, n_, m);
            if (jt == 0) {
                size_t off = ((size_t)(t - 1) * NB + b) * DS + col;
                o_qm[off] = m; o_qsd[off] = sd; o_qs[off] = qs;
            }
            saS[row * 168 + col] = f2bf(qs * ntp[b]);
        }
    } else {
        #pragma unroll
        for (int i = 0; i < 2; ++i) {
            int e = tx + i * 1024;
            int row = e >> 7, col = e & 127;
            saS[row * 168 + col] = f2bf(prev_state[(size_t)(b0 + row) * DS + col]);
        }
    }
    if (tx < 512) {
        int row = tx >> 5, ac = tx & 31;
        saS[row * 168 + 128 + ac] = f2bf(actions_t[(size_t)(b0 + row) * DA + ac]);
    }
    __syncthreads();

    // ---- X: x = relu([s|a] @ W_sa^T + b_sa), 4 tiles/wave -> base LDS ----
    {
        f4_t xacc[4];
        #pragma unroll
        for (int i = 0; i < 4; ++i) xacc[i] = (f4_t)0.0f;
        #pragma unroll
        for (int ks = 0; ks < 5; ++ks) {
            int ch = ks * 4 + kq;
            bf8_t a = sa8[ar * 21 + ch];
            #pragma unroll
            for (int i = 0; i < 4; ++i) {
                int tile = wv * 4 + i;
                bf8_t bfr = *(const bf8_t*)(Wsa_sw +
                    ((size_t)(tile * 20 + ch)) * 128 + ar * 8);
                xacc[i] = MFMA16(a, bfr, xacc[i]);
            }
        }
        #pragma unroll
        for (int i = 0; i < 4; ++i) {
            int col = (wv * 4 + i) * 16 + ar;
            float bj = b_sa[col];
            int chunk = col >> 3, el = col & 7;
            #pragma unroll
            for (int r = 0; r < 4; ++r) {
                int row = kq * 4 + r;
                R1s[row * 1024 + SWZ8(chunk, row) * 8 + el] =
                    f2bf(fmaxf(xacc[i][r] + bj, 0.0f));
            }
        }
    }
    __syncthreads();

    // ---- G: 6 gate GEMMs, K split over waves, B direct from global ----
    {
        const int kh = wv >> 3, wg = (wv >> 2) & 1, wn = wv & 3;
        f4_t acc[3];
        acc[0] = (f4_t)0.0f; acc[1] = (f4_t)0.0f; acc[2] = (f4_t)0.0f;
        const bf8_t* Asrc = wg ? hf8 : R18;
        const short* Wsw = wg ? Whh_sw : Wih_sw;
        #pragma unroll 4
        for (int k16 = 0; k16 < 16; ++k16) {
            int chunk = kh * 64 + k16 * 4 + kq;
            bf8_t a = Asrc[ar * 128 + SWZ8(chunk, ar)];
            #pragma unroll
            for (int g = 0; g < 3; ++g) {
                bf8_t bfr = *(const bf8_t*)(Wsw +
                    (((size_t)(g * 64 + jt * 4 + wn) * 128 + chunk) * 16 + ar) * 8);
                acc[g] = MFMA16(a, bfr, acc[g]);
            }
        }
        #pragma unroll
        for (int g = 0; g < 3; ++g)
            #pragma unroll
            for (int r = 0; r < 4; ++r)
                exg[((wv * 3 + g) * 16 + (kq * 4 + r)) * 16 + ar] = acc[g][r];
    }
    __syncthreads();
    // ---- distributed finisher: all 1024 threads, one (row,col) each ----
    {
        const int row = tx >> 6;               // = wave index, 16 rows
        const int col = tx & 63;
        const int wn2 = col >> 4, cl = col & 15;
        const int j = j0 + col;
        float gi[3], gh[3];
        #pragma unroll
        for (int g = 0; g < 3; ++g) {
            gi[g] = exg[(((0  + wn2) * 3 + g) * 16 + row) * 16 + cl]
                  + exg[(((8  + wn2) * 3 + g) * 16 + row) * 16 + cl];
            gh[g] = exg[(((4  + wn2) * 3 + g) * 16 + row) * 16 + cl]
                  + exg[(((12 + wn2) * 3 + g) * 16 + row) * 16 + cl];
        }
        const int b = b0 + row;
        const float ntv = ntp ? ntp[b] : 1.0f;
        const float h = belp[(size_t)b * DB + j] * ntv;
        const float rr = sigm(gi[0] + b_ih[j] + gh[0] + b_hh[j]);
        const float zz = sigm(gi[1] + b_ih[DB + j] + gh[1] + b_hh[DB + j]);
        const float nn = tanhf(gi[2] + b_ih[2 * DB + j] + rr * (gh[2] + b_hh[2 * DB + j]));
        const float nbv = (1.0f - zz) * nn + zz * h;
        bel_out[(size_t)b * DB + j] = nbv;     // coalesced per wave
        sPs[row * 64 + ((((col >> 3) ^ (row & 7)) << 3) | (col & 7))] = f2bf(nbv);
    }
    __syncthreads();
    // ---- P5: partial[jt] = nb_slice @ Wbqnb[:, K-slice jt]^T ----
    {
        f4_t pacc[4];
        #pragma unroll
        for (int i = 0; i < 4; ++i) pacc[i] = (f4_t)0.0f;
        #pragma unroll
        for (int ks = 0; ks < 2; ++ks) {
            int ch = ks * 4 + kq;
            bf8_t a = sP[ar * 8 + (ch ^ (ar & 7))];
            #pragma unroll
            for (int i = 0; i < 4; ++i) {
                int tile = wv * 4 + i;
                bf8_t bfr = *(const bf8_t*)(Wbqnb_sw +
                    (((size_t)tile * 128 + jt * 8 + ch) * 16 + ar) * 8);
                pacc[i] = MFMA16(a, bfr, pacc[i]);
            }
        }
        #pragma unroll
        for (int i = 0; i < 4; ++i) {
            int c = (wv * 4 + i) * 16 + ar;
            #pragma unroll
            for (int r = 0; r < 4; ++r)
                part_out[((size_t)jt * NB + b0 + kq * 4 + r) * DB + c] = f2bf(pacc[i][r]);
        }
    }
}

// ---------------------------------------------------------------------------
// khq63: hq[63] = relu(sum partials + obs_pre[63]) -> hqb bf16. (proven R6)
// ---------------------------------------------------------------------------
__global__ __launch_bounds__(256) void khq63(
    const short* __restrict__ partials, const short* __restrict__ obs_pre,
    short* __restrict__ hqb)
{
    const int row = blockIdx.x;
    const int c = threadIdx.x * 4;
    const ushort4 o = *(const ushort4*)(obs_pre + (size_t)row * DB + c);
    float s0 = bf2f(o.x), s1 = bf2f(o.y), s2 = bf2f(o.z), s3 = bf2f(o.w);
    for (int p = 0; p < 16; ++p) {
        const ushort4 v = *(const ushort4*)(partials + ((size_t)p * NB + row) * DB + c);
        s0 += bf2f(v.x); s1 += bf2f(v.y); s2 += bf2f(v.z); s3 += bf2f(v.w);
    }
    uint2 u;
    u.x = pack2(fmaxf(s0, 0.0f), fmaxf(s1, 0.0f));
    u.y = pack2(fmaxf(s2, 0.0f), fmaxf(s3, 0.0f));
    *(uint2*)(hqb + (size_t)row * DB + c) = u;
}

// ---------------------------------------------------------------------------
// kout: [mean|sd] = A @ W^T + b; softplus; sample. (proven; b-tile fastest)
// ---------------------------------------------------------------------------
__global__ __launch_bounds__(256) void kout(
    const short* __restrict__ A_, const short* __restrict__ W_,
    const float* __restrict__ bias, const float* __restrict__ noise,
    float* __restrict__ om, float* __restrict__ osd, float* __restrict__ os)
{
    __shared__ __align__(16) char smem[12288];
    const int tx = threadIdx.x;
    const int wv = tx >> 6, lane = tx & 63;
    const int b0 = blockIdx.x * 64, i0 = blockIdx.y * 16;
    const int wm = wv & 1, wn = wv >> 1;
    const bf8_t* A8 = (const bf8_t*)A_;
    const bf8_t* W8 = (const bf8_t*)W_;
    bf8_t* sA = (bf8_t*)smem;
    bf8_t* sB = sA + 512;
    f4_t acc[2];
    acc[0] = (f4_t)0.0f; acc[1] = (f4_t)0.0f;

    for (int kt = 0; kt < DH; kt += 64) {
        #pragma unroll
        for (int i = 0; i < 2; ++i) {
            int c = tx + i * 256;
            int row = c >> 3, ch = c & 7;
            sA[row * 8 + (ch ^ (row & 7))] = A8[(size_t)(b0 + row) * 128 + (kt >> 3) + ch];
        }
        {
            int row = tx >> 3, ch = tx & 7;
            int wr = (row < 16) ? (i0 + row) : (128 + i0 + (row - 16));
            sB[row * 8 + (ch ^ (row & 7))] = W8[(size_t)wr * 128 + (kt >> 3) + ch];
        }
        __syncthreads();
        #pragma unroll
        for (int ks = 0; ks < 2; ++ks) {
            int ch = ks * 4 + (lane >> 4);
            bf8_t a[2], b;
            #pragma unroll
            for (int mi = 0; mi < 2; ++mi) {
                int row = wm * 32 + mi * 16 + (lane & 15);
                a[mi] = sA[row * 8 + (ch ^ (row & 7))];
            }
            {
                int row = wn * 16 + (lane & 15);
                b = sB[row * 8 + (ch ^ (row & 7))];
            }
            acc[0] = MFMA16(a[0], b, acc[0]);
            acc[1] = MFMA16(a[1], b, acc[1]);
        }
        __syncthreads();
    }
    float* ebuf = (float*)smem;
    #pragma unroll
    for (int mi = 0; mi < 2; ++mi)
        #pragma unroll
        for (int r = 0; r < 4; ++r) {
            int row = wm * 32 + mi * 16 + (lane >> 4) * 4 + r;
            int col = wn * 16 + (lane & 15);
            ebuf[row * 32 + col] = acc[mi][r];
        }
    __syncthreads();
    {
        int bl = tx >> 2, p = tx & 3;
        int b = b0 + bl;
        float4 vm, vs, vx;
        #pragma unroll
        for (int k = 0; k < 4; ++k) {
            int i = p * 4 + k;
            float m_ = ebuf[bl * 32 + i] + bias[i0 + i];
            float sraw = ebuf[bl * 32 + 16 + i] + bias[128 + i0 + i];
            float sd = log1pf(__expf(-fabsf(sraw))) + fmaxf(sraw, 0.0f) + MIN_STD;
            float n_ = noise[(size_t)b * DS + i0 + i];
            ((float*)&vm)[k] = m_;
            ((float*)&vs)[k] = sd;
            ((float*)&vx)[k] = fmaf(sd, n_, m_);
        }
        size_t off = (size_t)b * DS + i0 + p * 4;
        *(float4*)(om + off)  = vm;
        *(float4*)(osd + off) = vs;
        *(float4*)(os + off)  = vx;
    }
}

// ---------------------------------------------------------------------------
// khp: hp = relu(beliefs @ W_bp^T + b_bp), 8192-row chunk. (proven)
// ---------------------------------------------------------------------------
__global__ __launch_bounds__(256) void khp(
    const float* __restrict__ belA, const short* __restrict__ Wbp_bf,
    const float* __restrict__ b_bp, short* __restrict__ hp_bf)
{
    __shared__ __align__(16) char smem[16384];
    const int tx = threadIdx.x;
    const int wv = tx >> 6, lane = tx & 63;
    const int b0 = blockIdx.x * 64, j0 = blockIdx.y * 64;
    const int wm = wv & 1, wn = wv >> 1;
    const bf8_t* Wp8 = (const bf8_t*)Wbp_bf;
    bf8_t* sA = (bf8_t*)smem;
    bf8_t* sB = sA + 512;
    f4_t acc[2][2];
    acc[0][0] = (f4_t)0.0f; acc[0][1] = (f4_t)0.0f;
    acc[1][0] = (f4_t)0.0f; acc[1][1] = (f4_t)0.0f;

    for (int kt = 0; kt < DB; kt += 64) {
        #pragma unroll
        for (int i = 0; i < 2; ++i) {
            int c = tx + i * 256;
            int row = c >> 3, ch = c & 7;
            const float4* p4 = (const float4*)(belA + (size_t)(b0 + row) * DB + kt + ch * 8);
            float4 f0 = p4[0], f1 = p4[1];
            bf8_t v;
            v[0]=f2bf(f0.x); v[1]=f2bf(f0.y); v[2]=f2bf(f0.z); v[3]=f2bf(f0.w);
            v[4]=f2bf(f1.x); v[5]=f2bf(f1.y); v[6]=f2bf(f1.z); v[7]=f2bf(f1.w);
            sA[row * 8 + (ch ^ (row & 7))] = v;
            sB[row * 8 + (ch ^ (row & 7))] = Wp8[(size_t)(j0 + row) * 128 + (kt >> 3) + ch];
        }
        __syncthreads();
        #pragma unroll
        for (int ks = 0; ks < 2; ++ks) {
            int ch = ks * 4 + (lane >> 4);
            bf8_t a[2], b[2];
            #pragma unroll
            for (int mi = 0; mi < 2; ++mi) {
                int row = wm * 32 + mi * 16 + (lane & 15);
                a[mi] = sA[row * 8 + (ch ^ (row & 7))];
            }
            #pragma unroll
            for (int ni = 0; ni < 2; ++ni) {
                int row = wn * 32 + ni * 16 + (lane & 15);
                b[ni] = sB[row * 8 + (ch ^ (row & 7))];
            }
            #pragma unroll
            for (int mi = 0; mi < 2; ++mi)
                #pragma unroll
                for (int ni = 0; ni < 2; ++ni)
                    acc[mi][ni] = MFMA16(a[mi], b[ni], acc[mi][ni]);
        }
        __syncthreads();
    }
    float* ebuf = (float*)smem;
    #pragma unroll
    for (int mi = 0; mi < 2; ++mi)
        #pragma unroll
        for (int ni = 0; ni < 2; ++ni)
            #pragma unroll
            for (int r = 0; r < 4; ++r) {
                int row = wm * 32 + mi * 16 + (lane >> 4) * 4 + r;
                int col = wn * 32 + ni * 16 + (lane & 15);
                ebuf[row * 64 + col] = fmaxf(acc[mi][ni][r] + b_bp[j0 + col], 0.0f);
            }
    __syncthreads();
    {
        int bl = tx >> 2, p = tx & 3;
        float* src = ebuf + bl * 64 + p * 16;
        short* dst = hp_bf + (size_t)(b0 + bl) * DH + j0 + p * 16;
        #pragma unroll
        for (int q = 0; q < 4; ++q) {
            uint2 u; u.x = pack2(src[q*4], src[q*4+1]); u.y = pack2(src[q*4+2], src[q*4+3]);
            *(uint2*)(dst + q * 4) = u;
        }
    }
}

// ---------------------------------------------------------------------------
extern "C" void kernel_launch(void* const* d_in, const int* in_sizes, int n_in,
                              void* d_out, int out_size, void* d_ws, size_t ws_size,
                              hipStream_t stream)
{
    const float* prev_state   = (const float*)d_in[0];
    const float* actions      = (const float*)d_in[1];
    const float* prev_belief  = (const float*)d_in[2];
    const float* observations = (const float*)d_in[3];
    const float* nonterm      = (const float*)d_in[4];
    const float* prior_noise  = (const float*)d_in[5];
    const float* post_noise   = (const float*)d_in[6];
    const float* W_sa = (const float*)d_in[7];
    const float* b_sa = (const float*)d_in[8];
    const float* W_ih = (const float*)d_in[9];
    const float* W_hh = (const float*)d_in[10];
    const float* b_ih = (const float*)d_in[11];
    const float* b_hh = (const float*)d_in[12];
    const float* W_bp = (const float*)d_in[13];
    const float* b_bp = (const float*)d_in[14];
    const float* W_sp = (const float*)d_in[15];
    const float* b_sp = (const float*)d_in[16];
    const float* W_bq = (const float*)d_in[17];
    const float* b_bq = (const float*)d_in[18];
    const float* W_sq = (const float*)d_in[19];
    const float* b_sq = (const float*)d_in[20];

    float* out     = (float*)d_out;
    float* beliefs = out;
    float* o_ps  = out + OUT_PS;
    float* o_pm  = out + OUT_PM;
    float* o_psd = out + OUT_PSD;
    float* o_qs  = out + OUT_QS;
    float* o_qm  = out + OUT_QM;
    float* o_qsd = out + OUT_QSD;

    // workspace (shorts)
    short* w = (short*)d_ws;
    short* Wbp_bf   = w;                                  // 1048576
    short* Wbq_bf   = Wbp_bf   + (size_t)1048576;         // 2097152
    short* Wsp_bf   = Wbq_bf   + (size_t)2097152;         // 262144
    short* Wsq_bf   = Wsp_bf   + (size_t)262144;          // 262144
    short* Wsq_sw   = Wsq_bf   + (size_t)262144;          // 262144
    short* Wsa_sw   = Wsq_sw   + (size_t)262144;          // 163840
    short* Wbqnb_sw = Wsa_sw   + (size_t)163840;          // 1048576
    short* Wih_sw   = Wbqnb_sw + (size_t)1048576;         // 3145728
    short* Whh_sw   = Wih_sw   + (size_t)3145728;         // 3145728
    short* obs_all  = Whh_sw   + (size_t)3145728;         // 16777216
    short* partials = obs_all  + (size_t)16777216;        // 8388608
    short* hqb      = partials + (size_t)8388608;         // 262144
    short* hp_bf    = partials;                           // tail reuse
    const size_t PART = (size_t)16 * NB * DB;

    k_cvt_all<<<5584, 256, 0, stream>>>(
        W_ih, W_hh, W_bp, W_bq, W_sp, W_sq, W_sa,
        Wbp_bf, Wbq_bf, Wsp_bf, Wsq_bf, Wsq_sw, Wsa_sw, Wbqnb_sw, Wih_sw, Whh_sw);

    // obs_pre for ALL 64 steps, one dispatch (b-tile fastest -> XCD-pinned A)
    kobs<<<dim3(256, 16), 256, 0, stream>>>(observations, Wbq_bf, b_bq, obs_all);

    for (int t = 0; t < NT; ++t) {
        const float* belp = (t == 0) ? prev_belief : beliefs + (size_t)(t - 1) * NB * DB;
        kstep<<<256, 1024, 0, stream>>>(
            t, prev_state, actions + (size_t)t * NB * DA,
            nonterm, post_noise,
            partials + ((t & 1) ^ 1) * PART,
            obs_all + (size_t)(t > 0 ? t - 1 : 0) * NB * DB,
            Wsq_sw, b_sq, Wsa_sw, b_sa,
            Wih_sw, Whh_sw, b_ih, b_hh, Wbqnb_sw,
            belp, beliefs + (size_t)t * NB * DB,
            partials + (t & 1) * PART,
            o_qm, o_qsd, o_qs);
    }

    // final-step posterior: hq[63] (sum partials) then outputs
    khq63<<<256, 256, 0, stream>>>(
        partials + ((NT - 1) & 1) * PART, obs_all + (size_t)(NT - 1) * NB * DB, hqb);
    kout<<<dim3(4, 8), 256, 0, stream>>>(
        hqb, Wsq_bf, b_sq, post_noise + (size_t)(NT - 1) * NB * DS,
        o_qm + (size_t)(NT - 1) * NB * DS, o_qsd + (size_t)(NT - 1) * NB * DS,
        o_qs + (size_t)(NT - 1) * NB * DS);

    // prior head: batched, 2 chunks of 8192 rows (hp reuses partials space)
    for (int c = 0; c < 2; ++c) {
        const size_t r0 = (size_t)c * 8192;
        khp<<<dim3(128, 16), 256, 0, stream>>>(
            beliefs + r0 * DB, Wbp_bf, b_bp, hp_bf);
        kout<<<dim3(128, 8), 256, 0, stream>>>(
            hp_bf, Wsp_bf, b_sp, prior_noise + r0 * DS,
            o_pm + r0 * DS, o_psd + r0 * DS, o_ps + r0 * DS);
    }
}